// Round 7
// baseline (122.947 us; speedup 1.0000x reference)
//
#include <hip/hip_runtime.h>
#include <cstdint>

typedef float   f32x4  __attribute__((ext_vector_type(4)));
typedef __bf16  bf16x4 __attribute__((ext_vector_type(4)));
typedef __bf16  bf16x8 __attribute__((ext_vector_type(8)));

#if __has_builtin(__builtin_amdgcn_exp2f)
#define EXP2F(x) __builtin_amdgcn_exp2f(x)
#else
#define EXP2F(x) exp2f(x)
#endif

#define BT_TOTAL 512
#define NNODES 170
#define CDIM 128
#define HEADS 8
#define HDIM 16
#define SLAB (NNODES*HDIM)           // 2720
#define NPAD 176                     // V^T row stride
#define VSLAB (HDIM*NPAD)            // 2816
#define QKV_ELEMS ((size_t)BT_TOTAL*HEADS*SLAB)
#define VT_ELEMS  ((size_t)BT_TOTAL*HEADS*VSLAB)
#define WPAD 136                     // qkv LDS W row stride
#define OPAD 136                     // fused-kernel LDS strides (16B-aligned)
#define S2L2E 0.12753851f            // log2(e)/sqrt(128), folded into Wq/bq

// ---------------------------------------------------------------- W -> bf16, k-swizzled
// wbf[mat][c][kk*32 + l4*8 + j] = W[mat][c][kk*32 + l4*4 + (j&3) + 16*(j>>2)]
__global__ __launch_bounds__(256) void wconv_kernel(const float* __restrict__ wq,
                                                    const float* __restrict__ wk,
                                                    const float* __restrict__ wv,
                                                    const float* __restrict__ wo,
                                                    __bf16* __restrict__ wbf) {
    int idx = blockIdx.x * 256 + threadIdx.x;
    if (idx >= 4 * 16384) return;
    int mat = idx >> 14, rem = idx & 16383;
    int c = rem >> 7, o = rem & 127;
    int kk = o >> 5, l4 = (o & 31) >> 3, j = o & 7;
    int col = kk * 32 + l4 * 4 + (j & 3) + 16 * (j >> 2);
    const float* W = (mat == 0) ? wq : (mat == 1) ? wk : (mat == 2) ? wv : wo;
    float scale = (mat == 0) ? S2L2E : 1.0f;
    wbf[idx] = (__bf16)(W[c * 128 + col] * scale);
}

// ---------------------------------------------------------------- fused QKV projection
// (round-5 structure, proven) 256 thr, 4 waves; wave w owns tiles {w, w+4, w+8(<11)}.
__global__ __launch_bounds__(256, 4) void qkv_kernel(const float* __restrict__ qin,
    const float* __restrict__ kin, const float* __restrict__ vin,
    const __bf16* __restrict__ wbf,
    const float* __restrict__ bq, const float* __restrict__ bk, const float* __restrict__ bv,
    __bf16* __restrict__ qws, __bf16* __restrict__ kws, __bf16* __restrict__ vt) {
    __shared__ __bf16 Wl[128 * WPAD];
    int t = threadIdx.x;
    int iid = blockIdx.x / BT_TOTAL;
    int bt  = blockIdx.x % BT_TOTAL;
    const float* X    = (iid == 0) ? qin : (iid == 1) ? kin : vin;
    const float* bias = (iid == 0) ? bq  : (iid == 1) ? bk  : bv;
    float wscale = (iid == 0) ? S2L2E : 1.0f;
    const __bf16* wb = wbf + iid * 16384;
    #pragma unroll
    for (int i = 0; i < 8; ++i) {
        int idx = i * 256 + t;
        int c = idx >> 4, x = (idx & 15) * 8;
        *(bf16x8*)&Wl[c * WPAD + x] = *(const bf16x8*)&wb[idx * 8];
    }
    __syncthreads();

    int w = t >> 6, lane = t & 63, li = lane & 15, l4 = lane >> 4;
    const f32x4 zf = {0.f, 0.f, 0.f, 0.f};

    auto loadA = [&](f32x4* A, int tile) {
        int mrow = tile * 16 + li;
        bool v = mrow < NNODES;
        const float* xr = X + ((size_t)(bt * NNODES + mrow)) * CDIM;
        #pragma unroll
        for (int kk = 0; kk < 4; ++kk) {
            A[2 * kk]     = v ? *(const f32x4*)(xr + kk * 32 + l4 * 4)      : zf;
            A[2 * kk + 1] = v ? *(const f32x4*)(xr + kk * 32 + l4 * 4 + 16) : zf;
        }
    };
    auto compute = [&](const f32x4* A, int tile) {
        f32x4 acc[8] = {};
        #pragma unroll
        for (int kk = 0; kk < 4; ++kk) {
            f32x4 a0 = A[2 * kk], a1 = A[2 * kk + 1];
            bf16x8 a = { (__bf16)a0[0], (__bf16)a0[1], (__bf16)a0[2], (__bf16)a0[3],
                         (__bf16)a1[0], (__bf16)a1[1], (__bf16)a1[2], (__bf16)a1[3] };
            #pragma unroll
            for (int nt = 0; nt < 8; ++nt) {
                bf16x8 b = *(const bf16x8*)&Wl[(nt * 16 + li) * WPAD + kk * 32 + l4 * 8];
                if (iid < 2)
                    acc[nt] = __builtin_amdgcn_mfma_f32_16x16x32_bf16(b, a, acc[nt], 0, 0, 0);
                else
                    acc[nt] = __builtin_amdgcn_mfma_f32_16x16x32_bf16(a, b, acc[nt], 0, 0, 0);
            }
        }
        if (iid < 2) {
            __bf16* dst = ((iid == 0) ? qws : kws) + (size_t)bt * HEADS * SLAB;
            int n = tile * 16 + li;
            if (n < NNODES) {
                #pragma unroll
                for (int nt = 0; nt < 8; ++nt) {
                    f32x4 b4 = *(const f32x4*)&bias[nt * 16 + l4 * 4];
                    f32x4 ov = acc[nt] + b4 * wscale;
                    bf16x4 o4 = { (__bf16)ov[0], (__bf16)ov[1], (__bf16)ov[2], (__bf16)ov[3] };
                    *(bf16x4*)&dst[(size_t)nt * SLAB + n * HDIM + l4 * 4] = o4;
                }
            }
        } else {
            __bf16* dst = vt + (size_t)bt * HEADS * VSLAB;
            int n0 = tile * 16 + l4 * 4;
            #pragma unroll
            for (int nt = 0; nt < 8; ++nt) {
                float bval = bias[nt * 16 + li];
                __bf16* d2 = dst + (size_t)nt * VSLAB + li * NPAD + n0;
                if (n0 + 3 < NNODES) {
                    bf16x4 o4 = { (__bf16)(acc[nt][0] + bval), (__bf16)(acc[nt][1] + bval),
                                  (__bf16)(acc[nt][2] + bval), (__bf16)(acc[nt][3] + bval) };
                    *(bf16x4*)d2 = o4;
                } else {
                    #pragma unroll
                    for (int rr = 0; rr < 4; ++rr)
                        if (n0 + rr < NNODES) d2[rr] = (__bf16)(acc[nt][rr] + bval);
                }
            }
        }
    };

    f32x4 A0[8], A1[8];
    loadA(A0, w);
    loadA(A1, w + 4);
    compute(A0, w);
    if (w < 3) loadA(A0, w + 8);
    compute(A1, w + 4);
    if (w < 3) compute(A0, w + 8);
}

// ---------------------------------------------------------------- fused attention + output projection
// block = bt (512 thr, 8 waves). Phase A: wave = head, O -> LDS (k-swizzled cols).
// Phase B: O @ Wo^T + bo -> out (nontemporal stores). LDS = 81,056 B -> 2 blocks/CU.
__global__ __launch_bounds__(512, 4) void attn_oproj_kernel(const __bf16* __restrict__ qws,
    const __bf16* __restrict__ kws, const __bf16* __restrict__ vt,
    const __bf16* __restrict__ wbf, const float* __restrict__ bo,
    float* __restrict__ out) {
    __shared__ __align__(16) __bf16 Wl[128 * OPAD];     // Wo, pre-swizzled rows
    __shared__ __align__(16) __bf16 oL[NNODES * OPAD];  // O, k-swizzled column order

    int bt = blockIdx.x;
    int t = threadIdx.x, w = t >> 6, lane = t & 63, li = lane & 15, l4 = lane >> 4;
    const __bf16 bz = (__bf16)0.0f;
    const bf16x4 z4 = {bz, bz, bz, bz};
    const f32x4 zf = {0.f, 0.f, 0.f, 0.f};

    // stage Wo (swizzled) into LDS
    const __bf16* wo = wbf + 3 * 16384;
    #pragma unroll
    for (int i = 0; i < 4; ++i) {
        int idx = i * 512 + t;
        int c = idx >> 4, x = (idx & 15) * 8;
        *(bf16x8*)&Wl[c * OPAD + x] = *(const bf16x8*)&wo[idx * 8];
    }

    // ================= phase A: attention, head = wave =================
    {
        int h = w;
        const __bf16* qb  = qws + ((size_t)(bt * HEADS + h)) * SLAB;
        const __bf16* kb  = kws + ((size_t)(bt * HEADS + h)) * SLAB;
        const __bf16* vtb = vt  + ((size_t)(bt * HEADS + h)) * VSLAB;

        bf16x4 kf[11];
        #pragma unroll
        for (int tt = 0; tt < 11; ++tt)
            kf[tt] = *(const bf16x4*)&kb[(tt * 16 + li) * HDIM + l4 * 4];

        bf16x8 vf[6];
        #pragma unroll
        for (int s = 0; s < 5; ++s) {
            bf16x4 a = *(const bf16x4*)&vtb[li * NPAD + 32 * s + 4 * l4];
            bf16x4 b = *(const bf16x4*)&vtb[li * NPAD + 32 * s + 4 * l4 + 16];
            vf[s] = __builtin_shufflevector(a, b, 0, 1, 2, 3, 4, 5, 6, 7);
        }
        {
            bf16x4 a = *(const bf16x4*)&vtb[li * NPAD + 160 + 4 * l4];
            bf16x8 v5 = { (160 + 4 * l4 + 0 < NNODES) ? a[0] : bz,
                          (160 + 4 * l4 + 1 < NNODES) ? a[1] : bz,
                          (160 + 4 * l4 + 2 < NNODES) ? a[2] : bz,
                          (160 + 4 * l4 + 3 < NNODES) ? a[3] : bz,
                          bz, bz, bz, bz };
            vf[5] = v5;
        }

        // O column base (k-swizzled): (h>>1)*32 + (h&1)*4 + l4*8
        int ocol = (h >> 1) * 32 + (h & 1) * 4 + l4 * 8;
        #pragma unroll 1
        for (int qc = 0; qc < 11; ++qc) {
            bf16x4 qv = *(const bf16x4*)&qb[(qc * 16 + li) * HDIM + l4 * 4];
            bf16x8 qf = __builtin_shufflevector(qv, z4, 0, 1, 2, 3, 4, 5, 6, 7);
            bf16x4 ph[11];
            f32x4 s4 = zf;
            #pragma unroll
            for (int tt = 0; tt < 11; ++tt) {
                bf16x8 a = __builtin_shufflevector(kf[tt], z4, 0, 1, 2, 3, 4, 5, 6, 7);
                f32x4 e = __builtin_amdgcn_mfma_f32_16x16x32_bf16(a, qf, zf, 0, 0, 0);
                if (tt == 10) {      // select BEFORE exp2: NaN-safe for unwritten K rows
                    #pragma unroll
                    for (int r = 0; r < 4; ++r)
                        e[r] = (160 + l4 * 4 + r < NNODES) ? e[r] : -1.0e30f;
                }
                f32x4 p;
                p[0] = EXP2F(e[0]); p[1] = EXP2F(e[1]);
                p[2] = EXP2F(e[2]); p[3] = EXP2F(e[3]);
                s4 += p;
                ph[tt] = __builtin_convertvector(p, bf16x4);
            }
            float sum = (s4[0] + s4[1]) + (s4[2] + s4[3]);
            sum += __shfl_xor(sum, 16);
            sum += __shfl_xor(sum, 32);
            float inv = 1.0f / sum;
            f32x4 o0 = zf, o1 = zf;
            o0 = __builtin_amdgcn_mfma_f32_16x16x32_bf16(vf[0],
                    __builtin_shufflevector(ph[0], ph[1], 0,1,2,3,4,5,6,7), o0, 0,0,0);
            o1 = __builtin_amdgcn_mfma_f32_16x16x32_bf16(vf[1],
                    __builtin_shufflevector(ph[2], ph[3], 0,1,2,3,4,5,6,7), o1, 0,0,0);
            o0 = __builtin_amdgcn_mfma_f32_16x16x32_bf16(vf[2],
                    __builtin_shufflevector(ph[4], ph[5], 0,1,2,3,4,5,6,7), o0, 0,0,0);
            o1 = __builtin_amdgcn_mfma_f32_16x16x32_bf16(vf[3],
                    __builtin_shufflevector(ph[6], ph[7], 0,1,2,3,4,5,6,7), o1, 0,0,0);
            o0 = __builtin_amdgcn_mfma_f32_16x16x32_bf16(vf[4],
                    __builtin_shufflevector(ph[8], ph[9], 0,1,2,3,4,5,6,7), o0, 0,0,0);
            o1 = __builtin_amdgcn_mfma_f32_16x16x32_bf16(vf[5],
                    __builtin_shufflevector(ph[10], z4,    0,1,2,3,4,5,6,7), o1, 0,0,0);
            f32x4 o = (o0 + o1) * inv;
            int q = qc * 16 + li;
            if (q < NNODES) {
                bf16x4 ov = { (__bf16)o[0], (__bf16)o[1], (__bf16)o[2], (__bf16)o[3] };
                *(bf16x4*)&oL[(size_t)q * OPAD + ocol] = ov;
            }
        }
    }
    __syncthreads();

    // ================= phase B: O @ Wo^T + bo -> out ====================
    for (int tile = w; tile < 11; tile += 8) {
        int mr = tile * 16 + li;
        if (mr > NNODES - 1) mr = NNODES - 1;       // clamp; stores guarded below
        f32x4 acc[8] = {};
        #pragma unroll
        for (int kk = 0; kk < 4; ++kk) {
            bf16x8 a = *(const bf16x8*)&oL[(size_t)mr * OPAD + kk * 32 + l4 * 8];
            #pragma unroll
            for (int nt = 0; nt < 8; ++nt) {
                bf16x8 b = *(const bf16x8*)&Wl[(nt * 16 + li) * OPAD + kk * 32 + l4 * 8];
                acc[nt] = __builtin_amdgcn_mfma_f32_16x16x32_bf16(b, a, acc[nt], 0, 0, 0);
            }
        }
        int n = tile * 16 + li;
        if (n < NNODES) {
            float* orow = out + ((size_t)bt * NNODES + n) * CDIM;
            #pragma unroll
            for (int nt = 0; nt < 8; ++nt) {
                f32x4 b4 = *(const f32x4*)&bo[nt * 16 + l4 * 4];
                f32x4 ov = acc[nt] + b4;
                __builtin_nontemporal_store(ov, (f32x4*)&orow[nt * 16 + l4 * 4]);
            }
        }
    }
}

// ---------------------------------------------------------------- launch
extern "C" void kernel_launch(void* const* d_in, const int* in_sizes, int n_in,
                              void* d_out, int out_size, void* d_ws, size_t ws_size,
                              hipStream_t stream) {
    const float* values = (const float*)d_in[0];
    const float* keys   = (const float*)d_in[1];
    const float* query  = (const float*)d_in[2];
    const float* Wv = (const float*)d_in[3];
    const float* bv = (const float*)d_in[4];
    const float* Wk = (const float*)d_in[5];
    const float* bk = (const float*)d_in[6];
    const float* Wq = (const float*)d_in[7];
    const float* bq = (const float*)d_in[8];
    const float* Wo = (const float*)d_in[9];
    const float* bo = (const float*)d_in[10];
    float* out = (float*)d_out;

    __bf16* qws = (__bf16*)d_ws;
    __bf16* kws = qws + QKV_ELEMS;
    __bf16* vt  = kws + QKV_ELEMS;
    __bf16* wbf = vt + VT_ELEMS;             // 4 x 16384 bf16, swizzled (+scaled Wq)
                                             // ws total ~67.9 MB (proven >= 89 MB available)

    hipLaunchKernelGGL(wconv_kernel, dim3(256),  dim3(256), 0, stream, Wq, Wk, Wv, Wo, wbf);
    hipLaunchKernelGGL(qkv_kernel,   dim3(1536), dim3(256), 0, stream,
                       query, keys, values, wbf, bq, bk, bv, qws, kws, vt);
    hipLaunchKernelGGL(attn_oproj_kernel, dim3(BT_TOTAL), dim3(512), 0, stream,
                       qws, kws, vt, wbf, bo, out);
}